// Round 10
// baseline (1519.401 us; speedup 1.0000x reference)
//
#include <hip/hip_runtime.h>
#include <hip/hip_bf16.h>
#include <math.h>

#define D 128
#define NGRAPH 16

typedef __attribute__((ext_vector_type(8))) short bf16x8;   // 8 bf16 (4 VGPRs)
typedef __attribute__((ext_vector_type(4))) float f32x4;    // MFMA C/D

// Contraction-dim permutation (internal only): permuted index c' holds
// original col pi(c') = (c'>>6)*64 + (c'&3)*16 + ((c'>>2)&15).
// x3 lives only in LDS (permuted cols); W4n's contraction dim is permuted to
// match; u and xb are stored in ORIGINAL column order -> no unpermute anywhere.

__device__ __forceinline__ float bflo(unsigned u) {
    union { unsigned i; float f; } v; v.i = u << 16; return v.f;
}
__device__ __forceinline__ float bfhi(unsigned u) {
    union { unsigned i; float f; } v; v.i = u & 0xffff0000u; return v.f;
}
__device__ __forceinline__ float bfbits(unsigned short us) {
    union { unsigned i; float f; } v; v.i = ((unsigned)us) << 16; return v.f;
}
__device__ __forceinline__ unsigned pack_bf16(float x, float y) {
    __hip_bfloat16 hx = __float2bfloat16(x);
    __hip_bfloat16 hy = __float2bfloat16(y);
    unsigned ux = *(const unsigned short*)&hx;
    unsigned uy = *(const unsigned short*)&hy;
    return ux | (uy << 16);
}
__device__ __forceinline__ int unperm(int cp) {
    return (cp >> 6) * 64 + (cp & 3) * 16 + ((cp >> 2) & 15);
}

// ---------------------------------------------------------------------------
// Stage A: edge count by dst + per-graph node counts + weight prep:
//   Wbt3[c][k] = W3[k][c] bf16 ;  W4n[k][c'] = W4[k][pi(c')] bf16
//   w5p[c'] = W5[pi(c')] ;  b45p[c'] = b4[pi(c')] + b5[pi(c')]
// ---------------------------------------------------------------------------
__global__ void count_wconv_kernel(const int* __restrict__ dstIdx,
                                   int* __restrict__ cnt, int E,
                                   const int* __restrict__ batch,
                                   float* __restrict__ cntn, int N,
                                   const float* __restrict__ W3,
                                   const float* __restrict__ W4,
                                   const float* __restrict__ W5,
                                   const float* __restrict__ b4,
                                   const float* __restrict__ b5,
                                   __hip_bfloat16* __restrict__ Wbt3,
                                   __hip_bfloat16* __restrict__ W4n,
                                   float* __restrict__ w5p,
                                   float* __restrict__ b45p)
{
    int id = blockIdx.x * 256 + threadIdx.x;
    if (id < E) atomicAdd(&cnt[dstIdx[id]], 1);
    if (id < N) atomicAdd(&cntn[batch[id]], 1.0f);   // sorted -> wave-coalesced
    if (id < D * D) {
        int c = id >> 7, k = id & 127;
        Wbt3[id] = __float2bfloat16(W3[k * D + c]);
        W4n[id]  = __float2bfloat16(W4[c * D + unperm(k)]);  // row c=k-out, col k=c'
    }
    if (id < D) {
        int c = unperm(id);
        w5p[id]  = W5[c];
        b45p[id] = b4[c] + b5[c];
    }
}

// ---------------------------------------------------------------------------
// Stage B: chained GEMMs. Pass1: x3 = Xs@W3 + b3 (kept in LDS, permuted cols;
// p,q' = x3.W5 / x3.(b4+b5) reduced + atomicAdd'ed to pq). Pass2: u = x3@W4^T
// (contraction over permuted cols), repacked via LDS to ORIGINAL k order.
// xb = bf16(X) written directly from the staging registers (original order).
// Tail: per-graph column sums of X (xsum) via sorted-batch run trick.
// ---------------------------------------------------------------------------
__global__ __launch_bounds__(512, 4) void proj10_kernel(
    const float* __restrict__ X,
    const __hip_bfloat16* __restrict__ Wbt3,
    const __hip_bfloat16* __restrict__ W4n,
    const float* __restrict__ b3,
    const float* __restrict__ w5p, const float* __restrict__ b45p,
    const int* __restrict__ batch,
    unsigned* __restrict__ xb,       // [N][64] uints, original cols
    unsigned* __restrict__ ub,       // [N][64] uints, original k
    float* __restrict__ pq,          // [N][2], pre-zeroed
    float* __restrict__ xsum,        // [16][128] fp32, pre-zeroed
    int N)
{
    __shared__ __hip_bfloat16 Xs[128][136];
    __shared__ __hip_bfloat16 X3s[128][136];
    __shared__ int batch_s[128];

    const int nodeBase = blockIdx.x * 128;
    const int tid      = threadIdx.x;

    // ---- stage X -> Xs (bf16) and write xb directly (coalesced) ----
    {
        int r   = tid >> 2;
        int qq  = tid & 3;
        int row = nodeBase + r;
        int rowc = (row < N) ? row : N - 1;
        const float* src = X + (size_t)rowc * D + qq * 32;
        uint4 packs[4];
        #pragma unroll
        for (int i = 0; i < 4; ++i) {
            float4 u = *(const float4*)(src + i * 8);
            float4 v = *(const float4*)(src + i * 8 + 4);
            packs[i].x = pack_bf16(u.x, u.y);
            packs[i].y = pack_bf16(u.z, u.w);
            packs[i].z = pack_bf16(v.x, v.y);
            packs[i].w = pack_bf16(v.z, v.w);
            *(uint4*)&Xs[r][qq * 32 + i * 8] = packs[i];
        }
        if (row < N) {
            uint4* dst = (uint4*)(xb + (size_t)row * 64 + qq * 16);
            #pragma unroll
            for (int i = 0; i < 4; ++i) dst[i] = packs[i];
        }
        if (tid < 128) {
            int rr = nodeBase + tid;
            batch_s[tid] = (rr < N) ? batch[rr] : 0;
        }
    }
    __syncthreads();

    const int wv   = tid >> 6;        // 0..7
    const int lane = tid & 63;
    const int wr   = (wv >> 1) * 32;  // 32 rows per wave
    const int half = wv & 1;
    const int wc   = half * 64;
    const int fr   = lane & 15;
    const int fq   = lane >> 4;

    bf16x8 a[4][2];
    #pragma unroll
    for (int kk = 0; kk < 4; ++kk)
        #pragma unroll
        for (int mf = 0; mf < 2; ++mf)
            a[kk][mf] = *(const bf16x8*)&Xs[wr + mf * 16 + fr][kk * 32 + fq * 8];

    float4 w5v  = *(const float4*)(w5p  + half * 64 + fr * 4);
    float4 b45v = *(const float4*)(b45p + half * 64 + fr * 4);

    // ---- pass 1: x3 ----
    {
        f32x4 acc[2][4] = {};
        #pragma unroll
        for (int kk = 0; kk < 4; ++kk) {
            bf16x8 b[4];
            #pragma unroll
            for (int nf = 0; nf < 4; ++nf)
                b[nf] = *(const bf16x8*)(Wbt3 + (size_t)(wc + nf * 16 + fr) * D
                                              + kk * 32 + fq * 8);
            #pragma unroll
            for (int mf = 0; mf < 2; ++mf)
                #pragma unroll
                for (int nf = 0; nf < 4; ++nf)
                    acc[mf][nf] = __builtin_amdgcn_mfma_f32_16x16x32_bf16(
                        a[kk][mf], b[nf], acc[mf][nf], 0, 0, 0);
        }
        float bv[4];
        #pragma unroll
        for (int nf = 0; nf < 4; ++nf) bv[nf] = b3[wc + nf * 16 + fr];

        #pragma unroll
        for (int mf = 0; mf < 2; ++mf) {
            #pragma unroll
            for (int j = 0; j < 4; ++j) {
                int rl  = wr + mf * 16 + fq * 4 + j;
                int row = nodeBase + rl;
                float c0 = acc[mf][0][j] + bv[0];
                float c1 = acc[mf][1][j] + bv[1];
                float c2 = acc[mf][2][j] + bv[2];
                float c3 = acc[mf][3][j] + bv[3];
                uint2 v;
                v.x = pack_bf16(c0, c1);
                v.y = pack_bf16(c2, c3);
                *(uint2*)&X3s[rl][half * 64 + fr * 4] = v;   // permuted cols
                float vp = c0 * w5v.x + c1 * w5v.y + c2 * w5v.z + c3 * w5v.w;
                float vq = c0 * b45v.x + c1 * b45v.y + c2 * b45v.z + c3 * b45v.w;
                #pragma unroll
                for (int off = 1; off < 16; off <<= 1) {
                    vp += __shfl_xor(vp, off);
                    vq += __shfl_xor(vq, off);
                }
                if (fr == 0 && row < N) {
                    atomicAdd(&pq[2 * row],     vp);
                    atomicAdd(&pq[2 * row + 1], vq);
                }
            }
        }
    }
    __syncthreads();

    // ---- pass 2: u = x3 @ W4^T ----
    bf16x8 a2[4][2];
    #pragma unroll
    for (int kk = 0; kk < 4; ++kk)
        #pragma unroll
        for (int mf = 0; mf < 2; ++mf)
            a2[kk][mf] = *(const bf16x8*)&X3s[wr + mf * 16 + fr][kk * 32 + fq * 8];
    __syncthreads();          // all a2 reads done before repack overwrites X3s
    {
        f32x4 acc[2][4] = {};
        #pragma unroll
        for (int kk = 0; kk < 4; ++kk) {
            bf16x8 b[4];
            #pragma unroll
            for (int nf = 0; nf < 4; ++nf)
                b[nf] = *(const bf16x8*)(W4n + (size_t)(wc + nf * 16 + fr) * D
                                             + kk * 32 + fq * 8);
            #pragma unroll
            for (int mf = 0; mf < 2; ++mf)
                #pragma unroll
                for (int nf = 0; nf < 4; ++nf)
                    acc[mf][nf] = __builtin_amdgcn_mfma_f32_16x16x32_bf16(
                        a2[kk][mf], b[nf], acc[mf][nf], 0, 0, 0);
        }
        // repack u into X3s at ORIGINAL k order: k = half*64 + nf*16 + fr
        #pragma unroll
        for (int mf = 0; mf < 2; ++mf)
            #pragma unroll
            for (int nf = 0; nf < 4; ++nf)
                #pragma unroll
                for (int j = 0; j < 4; ++j)
                    X3s[wr + mf * 16 + fq * 4 + j][half * 64 + nf * 16 + fr] =
                        __float2bfloat16(acc[mf][nf][j]);
    }
    __syncthreads();

    // ---- readout u (coalesced) ----
    {
        int r   = tid >> 2;
        int qq  = tid & 3;
        int row = nodeBase + r;
        if (row < N) {
            uint4* dst = (uint4*)(ub + (size_t)row * 64 + qq * 16);
            const uint4* s = (const uint4*)&X3s[r][qq * 32];
            #pragma unroll
            for (int i = 0; i < 4; ++i) dst[i] = s[i];
        }
    }

    // ---- per-graph column sums of X ----
    if (tid < 128) {
        int nv = N - nodeBase; if (nv > 128) nv = 128;
        float s = 0.f; int gcur = -1;
        for (int r = 0; r < nv; ++r) {
            int gg = batch_s[r];
            float v = bfbits(*(const unsigned short*)&Xs[r][tid]);
            if (gg != gcur) {
                if (gcur >= 0) atomicAdd(&xsum[gcur * D + tid], s);
                gcur = gg; s = 0.f;
            }
            s += v;
        }
        if (gcur >= 0) atomicAdd(&xsum[gcur * D + tid], s);
    }
}

// ---------------------------------------------------------------------------
// Stage C: scans
// ---------------------------------------------------------------------------
__global__ __launch_bounds__(256) void scan1(const int* __restrict__ cnt,
                                             int* __restrict__ row_off,
                                             int* __restrict__ bsum, int N)
{
    __shared__ int s[256];
    int tid = threadIdx.x;
    int i0  = blockIdx.x * 1024 + tid * 4;
    int v[4];
    #pragma unroll
    for (int j = 0; j < 4; ++j) v[j] = (i0 + j < N) ? cnt[i0 + j] : 0;
    int t = v[0] + v[1] + v[2] + v[3];
    s[tid] = t;
    __syncthreads();
    for (int off = 1; off < 256; off <<= 1) {
        int y = 0;
        if (tid >= off) y = s[tid - off];
        __syncthreads();
        s[tid] += y;
        __syncthreads();
    }
    int run = s[tid] - t;
    #pragma unroll
    for (int j = 0; j < 4; ++j) {
        if (i0 + j < N) row_off[i0 + j] = run;
        run += v[j];
    }
    if (tid == 255) bsum[blockIdx.x] = s[255];
}

__global__ void scan2(int* __restrict__ bsum, int nb)
{
    int lane = threadIdx.x;  // blockDim = 64
    int a = (lane < nb) ? bsum[lane] : 0;
    int b = (64 + lane < nb) ? bsum[64 + lane] : 0;
    int xa = a;
    #pragma unroll
    for (int off = 1; off < 64; off <<= 1) {
        int y = __shfl_up(xa, off);
        if (lane >= off) xa += y;
    }
    int totA = __shfl(xa, 63);
    int xb2 = b;
    #pragma unroll
    for (int off = 1; off < 64; off <<= 1) {
        int y = __shfl_up(xb2, off);
        if (lane >= off) xb2 += y;
    }
    if (lane < nb) bsum[lane] = xa - a;
    if (64 + lane < nb) bsum[64 + lane] = totA + xb2 - b;
}

// ---------------------------------------------------------------------------
// Stage D: fill (row_off doubles as cursor; node recovers start later)
// ---------------------------------------------------------------------------
__global__ void fill_kernel(const int* __restrict__ srcIdx,
                            const int* __restrict__ dstIdx,
                            const float* __restrict__ eattr,
                            int* __restrict__ row_off,
                            const int* __restrict__ bsum,
                            int2* __restrict__ src_attr, int E)
{
    int e = blockIdx.x * 256 + threadIdx.x;
    if (e < E) {
        int d = dstIdx[e];
        int p = atomicAdd(&row_off[d], 1);
        int2 rec;
        rec.x = srcIdx[e];
        rec.y = __float_as_int(eattr[e]);
        src_attr[p + bsum[d >> 10]] = rec;
    }
}

// ---------------------------------------------------------------------------
// Stage E: per-dst-node attention + aggregation + in-kernel mean-pool of
// z = sum alpha * X[src]. One wave per node (grid-strided chunk per block),
// single uint2 gather per edge per lane (xb serves dot AND value).
// Per-block 16x128 LDS pool accumulator, flushed once per block.
// ---------------------------------------------------------------------------
__global__ __launch_bounds__(256) void node_kernel(
    const unsigned* __restrict__ xb,           // [N][64]
    const unsigned* __restrict__ ub,           // [N][64]
    const float* __restrict__ pq,              // [N][2]
    const int* __restrict__ row_off,
    const int* __restrict__ cnt,
    const int* __restrict__ bsum,
    const int2* __restrict__ src_attr,
    const int* __restrict__ batch,
    float* __restrict__ poolZ,                 // [16][128], pre-zeroed
    float* __restrict__ cnt2g,                 // [16], pre-zeroed
    int N, int chunk)
{
    __shared__ float zs[NGRAPH * D];
    __shared__ float c2s[NGRAPH];
    for (int i = threadIdx.x; i < NGRAPH * D; i += 256) zs[i] = 0.f;
    if (threadIdx.x < NGRAPH) c2s[threadIdx.x] = 0.f;
    __syncthreads();

    const int wv   = threadIdx.x >> 6;
    const int lane = threadIdx.x & 63;
    const int h    = lane >> 5;
    const int l5   = lane & 31;
    const float inv_sqrt_d = 0.08838834764831845f;  // 1/sqrt(128)

    int startN = blockIdx.x * chunk;
    int endN   = min(startN + chunk, N);

    for (int n = startN + wv; n < endN; n += 4) {
        int deg = cnt[n];
        if (deg <= 0) continue;                // wave-uniform

        uint2 uu = *(const uint2*)(ub + (size_t)n * 64 + l5 * 2);
        float u0 = bflo(uu.x), u1 = bfhi(uu.x), u2 = bflo(uu.y), u3 = bfhi(uu.y);
        float pv = pq[2 * n], qv = pq[2 * n + 1];
        const int2* sa = src_attr + (row_off[n] + bsum[n >> 10] - deg);

        float mrun = -INFINITY, z = 0.f;
        float acc0 = 0.f, acc1 = 0.f, acc2 = 0.f, acc3 = 0.f;

        for (int i = 0; i < deg; i += 4) {
            int e0 = i + h;
            int e1 = i + 2 + h;
            int2 r0 = sa[min(e0, deg - 1)];
            int2 r1 = sa[min(e1, deg - 1)];
            uint2 f0 = *(const uint2*)(xb + (size_t)r0.x * 64 + l5 * 2);
            uint2 f1 = *(const uint2*)(xb + (size_t)r1.x * 64 + l5 * 2);

            float d0 = u0 * bflo(f0.x) + u1 * bfhi(f0.x) + u2 * bflo(f0.y) + u3 * bfhi(f0.y);
            float d1 = u0 * bflo(f1.x) + u1 * bfhi(f1.x) + u2 * bflo(f1.y) + u3 * bfhi(f1.y);
            #pragma unroll
            for (int off = 16; off; off >>= 1) {
                d0 += __shfl_xor(d0, off);
                d1 += __shfl_xor(d1, off);
            }
            float s0 = (d0 + __int_as_float(r0.y) * pv + qv) * inv_sqrt_d;
            float s1 = (d1 + __int_as_float(r1.y) * pv + qv) * inv_sqrt_d;
            if (e0 >= deg) s0 = -INFINITY;
            if (e1 >= deg) s1 = -INFINITY;

            float tm = fmaxf(s0, s1);
            tm = fmaxf(tm, __shfl_xor(tm, 32));
            if (tm > mrun) {                   // wave-uniform rescale branch
                float sc = __expf(mrun - tm);  // 0 on first iteration
                z *= sc; acc0 *= sc; acc1 *= sc; acc2 *= sc; acc3 *= sc;
                mrun = tm;
            }
            float w0 = __expf(s0 - mrun);      // 0 for masked edges
            float w1 = __expf(s1 - mrun);
            z += w0 + w1;
            acc0 += w0 * bflo(f0.x) + w1 * bflo(f1.x);
            acc1 += w0 * bfhi(f0.x) + w1 * bfhi(f1.x);
            acc2 += w0 * bflo(f0.y) + w1 * bflo(f1.y);
            acc3 += w0 * bfhi(f0.y) + w1 * bfhi(f1.y);
        }

        z    += __shfl_xor(z, 32);
        acc0 += __shfl_xor(acc0, 32);
        acc1 += __shfl_xor(acc1, 32);
        acc2 += __shfl_xor(acc2, 32);
        acc3 += __shfl_xor(acc3, 32);

        if (h == 0) {
            float inv = 1.f / z;
            int g = batch[n];
            float* zr = zs + g * D + l5 * 4;
            atomicAdd(zr + 0, acc0 * inv);
            atomicAdd(zr + 1, acc1 * inv);
            atomicAdd(zr + 2, acc2 * inv);
            atomicAdd(zr + 3, acc3 * inv);
            if (l5 == 0) atomicAdd(&c2s[g], 1.f);
        }
    }
    __syncthreads();
    for (int i = threadIdx.x; i < NGRAPH * D; i += 256) {
        float v = zs[i];
        if (v != 0.f) atomicAdd(&poolZ[i], v);
    }
    if (threadIdx.x < NGRAPH) {
        float v = c2s[threadIdx.x];
        if (v != 0.f) atomicAdd(&cnt2g[threadIdx.x], v);
    }
}

// ---------------------------------------------------------------------------
// final: out[g][c] = (xsum.W1col + cntn*b1 + Zsum.W2col + cnt2*b2) / max(cntn,1)
// ---------------------------------------------------------------------------
__global__ void final_kernel(const float* __restrict__ xsum,
                             const float* __restrict__ poolZ,
                             const float* __restrict__ cntn,
                             const float* __restrict__ cnt2g,
                             const float* __restrict__ W1,
                             const float* __restrict__ b1,
                             const float* __restrict__ W2,
                             const float* __restrict__ b2,
                             float* __restrict__ out)
{
    int i = blockIdx.x * 256 + threadIdx.x;
    if (i < NGRAPH * D) {
        int g = i >> 7;
        int c = i & 127;
        float s1 = 0.f, s2 = 0.f;
        for (int k = 0; k < D; ++k) {
            s1 += xsum[g * D + k]  * W1[k * D + c];
            s2 += poolZ[g * D + k] * W2[k * D + c];
        }
        float cval = cntn[g];
        out[i] = (s1 + cval * b1[c] + s2 + cnt2g[g] * b2[c]) / fmaxf(cval, 1.f);
    }
}

// ---------------------------------------------------------------------------
extern "C" void kernel_launch(void* const* d_in, const int* in_sizes, int n_in,
                              void* d_out, int out_size, void* d_ws, size_t ws_size,
                              hipStream_t stream)
{
    const float* x     = (const float*)d_in[0];
    const int*   eidx  = (const int*)d_in[1];   // [2,E]: src = eidx[e], dst = eidx[E+e]
    const float* eattr = (const float*)d_in[2];
    const int*   batch = (const int*)d_in[3];
    const float* W1 = (const float*)d_in[4];  const float* b1 = (const float*)d_in[5];
    const float* W2 = (const float*)d_in[6];  const float* b2 = (const float*)d_in[7];
    const float* W3 = (const float*)d_in[8];  const float* b3 = (const float*)d_in[9];
    const float* W4 = (const float*)d_in[10]; const float* b4 = (const float*)d_in[11];
    const float* W5 = (const float*)d_in[12]; const float* b5 = (const float*)d_in[13];
    float* out = (float*)d_out;

    const int N = in_sizes[0] / D;
    const int E = in_sizes[1] / 2;

    // workspace layout
    char* ws = (char*)d_ws;
    unsigned* xb = (unsigned*)ws;                           // [N][64]
    unsigned* ub = xb + (size_t)N * 64;                     // [N][64]
    int* cnt      = (int*)(ub + (size_t)N * 64);
    int* row_off  = cnt + N;
    int2* src_attr = (int2*)(row_off + N);
    int* bsum     = (int*)(src_attr + E);
    // zero region: poolZ | xsum | cntn | cnt2 | pq
    float* poolZ = (float*)(bsum + 256);
    float* xsum  = poolZ + NGRAPH * D;
    float* cntn  = xsum + NGRAPH * D;
    float* cnt2g = cntn + NGRAPH;
    float* pq    = cnt2g + NGRAPH;                          // [N][2]
    __hip_bfloat16* Wbt3 = (__hip_bfloat16*)(pq + 2 * (size_t)N);
    __hip_bfloat16* W4n  = Wbt3 + D * D;
    float* w5p  = (float*)(W4n + D * D);
    float* b45p = w5p + D;

    size_t zero_floats = (size_t)(2 * NGRAPH * D + 2 * NGRAPH) + 2 * (size_t)N;
    hipMemsetAsync(cnt, 0, (size_t)N * sizeof(int), stream);
    hipMemsetAsync(poolZ, 0, zero_floats * sizeof(float), stream);

    count_wconv_kernel<<<(E + 255) / 256, 256, 0, stream>>>(
        eidx + E, cnt, E, batch, cntn, N, W3, W4, W5, b4, b5,
        Wbt3, W4n, w5p, b45p);

    int nb = (N + 1023) / 1024;
    scan1<<<nb, 256, 0, stream>>>(cnt, row_off, bsum, N);
    scan2<<<1, 64, 0, stream>>>(bsum, nb);
    fill_kernel<<<(E + 255) / 256, 256, 0, stream>>>(eidx, eidx + E, eattr,
                                                     row_off, bsum, src_attr, E);

    proj10_kernel<<<(N + 127) / 128, 512, 0, stream>>>(x, Wbt3, W4n, b3,
                                                       w5p, b45p, batch,
                                                       xb, ub, pq, xsum, N);

    const int nodeBlocks = 2048;
    int chunk = (N + nodeBlocks - 1) / nodeBlocks;
    node_kernel<<<nodeBlocks, 256, 0, stream>>>(xb, ub, pq, row_off, cnt, bsum,
                                                src_attr, batch, poolZ, cnt2g,
                                                N, chunk);

    final_kernel<<<(NGRAPH * D + 255) / 256, 256, 0, stream>>>(
        xsum, poolZ, cntn, cnt2g, W1, b1, W2, b2, out);
}

// Round 11
// 264.921 us; speedup vs baseline: 5.7353x; 5.7353x over previous
//
#include <hip/hip_runtime.h>
#include <hip/hip_bf16.h>
#include <math.h>

#define D 128
#define NGRAPH 16

typedef __attribute__((ext_vector_type(8))) short bf16x8;   // 8 bf16 (4 VGPRs)
typedef __attribute__((ext_vector_type(4))) float f32x4;    // MFMA C/D

// Contraction-dim permutation (internal only): permuted index c' holds
// original col pi(c') = (c'>>6)*64 + (c'&3)*16 + ((c'>>2)&15).
// x3 lives only in LDS (permuted cols); W4n's contraction dim is permuted to
// match; u and xb are stored in ORIGINAL column order -> no unpermute anywhere.

__device__ __forceinline__ float bflo(unsigned u) {
    union { unsigned i; float f; } v; v.i = u << 16; return v.f;
}
__device__ __forceinline__ float bfhi(unsigned u) {
    union { unsigned i; float f; } v; v.i = u & 0xffff0000u; return v.f;
}
__device__ __forceinline__ float bfbits(unsigned short us) {
    union { unsigned i; float f; } v; v.i = ((unsigned)us) << 16; return v.f;
}
__device__ __forceinline__ unsigned pack_bf16(float x, float y) {
    __hip_bfloat16 hx = __float2bfloat16(x);
    __hip_bfloat16 hy = __float2bfloat16(y);
    unsigned ux = *(const unsigned short*)&hx;
    unsigned uy = *(const unsigned short*)&hy;
    return ux | (uy << 16);
}
__device__ __forceinline__ int unperm(int cp) {
    return (cp >> 6) * 64 + (cp & 3) * 16 + ((cp >> 2) & 15);
}

// ---------------------------------------------------------------------------
// Stage A: edge count by dst + weight prep (NO per-graph float atomics here;
// that was a 1.2ms atomic storm — 100k float atomics on 16 addresses):
//   Wbt3[c][k] = W3[k][c] bf16 ;  W4n[k][c'] = W4[k][pi(c')] bf16
//   w5p[c'] = W5[pi(c')] ;  b45p[c'] = b4[pi(c')] + b5[pi(c')]
// ---------------------------------------------------------------------------
__global__ void count_wconv_kernel(const int* __restrict__ dstIdx,
                                   int* __restrict__ cnt, int E,
                                   const float* __restrict__ W3,
                                   const float* __restrict__ W4,
                                   const float* __restrict__ W5,
                                   const float* __restrict__ b4,
                                   const float* __restrict__ b5,
                                   __hip_bfloat16* __restrict__ Wbt3,
                                   __hip_bfloat16* __restrict__ W4n,
                                   float* __restrict__ w5p,
                                   float* __restrict__ b45p)
{
    int id = blockIdx.x * 256 + threadIdx.x;
    if (id < E) atomicAdd(&cnt[dstIdx[id]], 1);
    if (id < D * D) {
        int c = id >> 7, k = id & 127;
        Wbt3[id] = __float2bfloat16(W3[k * D + c]);
        W4n[id]  = __float2bfloat16(W4[c * D + unperm(k)]);  // row c=k-out, col k=c'
    }
    if (id < D) {
        int c = unperm(id);
        w5p[id]  = W5[c];
        b45p[id] = b4[c] + b5[c];
    }
}

// ---------------------------------------------------------------------------
// Stage B: chained GEMMs. Pass1: x3 = Xs@W3 + b3 (kept in LDS, permuted cols;
// p,q' = x3.W5 / x3.(b4+b5) reduced + atomicAdd'ed to pq). Pass2: u = x3@W4^T
// (contraction over permuted cols), repacked via LDS to ORIGINAL k order.
// xb = bf16(X) written directly from the staging registers (original order).
// Tail: per-graph column sums of X (xsum) + node counts (cntn, tid==0 only,
// one atomic per graph-run per block) via sorted-batch run trick.
// ---------------------------------------------------------------------------
__global__ __launch_bounds__(512, 4) void proj10_kernel(
    const float* __restrict__ X,
    const __hip_bfloat16* __restrict__ Wbt3,
    const __hip_bfloat16* __restrict__ W4n,
    const float* __restrict__ b3,
    const float* __restrict__ w5p, const float* __restrict__ b45p,
    const int* __restrict__ batch,
    unsigned* __restrict__ xb,       // [N][64] uints, original cols
    unsigned* __restrict__ ub,       // [N][64] uints, original k
    float* __restrict__ pq,          // [N][2], pre-zeroed
    float* __restrict__ xsum,        // [16][128] fp32, pre-zeroed
    float* __restrict__ cntn,        // [16] fp32, pre-zeroed
    int N)
{
    __shared__ __hip_bfloat16 Xs[128][136];
    __shared__ __hip_bfloat16 X3s[128][136];
    __shared__ int batch_s[128];

    const int nodeBase = blockIdx.x * 128;
    const int tid      = threadIdx.x;

    // ---- stage X -> Xs (bf16) and write xb directly (coalesced) ----
    {
        int r   = tid >> 2;
        int qq  = tid & 3;
        int row = nodeBase + r;
        int rowc = (row < N) ? row : N - 1;
        const float* src = X + (size_t)rowc * D + qq * 32;
        uint4 packs[4];
        #pragma unroll
        for (int i = 0; i < 4; ++i) {
            float4 u = *(const float4*)(src + i * 8);
            float4 v = *(const float4*)(src + i * 8 + 4);
            packs[i].x = pack_bf16(u.x, u.y);
            packs[i].y = pack_bf16(u.z, u.w);
            packs[i].z = pack_bf16(v.x, v.y);
            packs[i].w = pack_bf16(v.z, v.w);
            *(uint4*)&Xs[r][qq * 32 + i * 8] = packs[i];
        }
        if (row < N) {
            uint4* dst = (uint4*)(xb + (size_t)row * 64 + qq * 16);
            #pragma unroll
            for (int i = 0; i < 4; ++i) dst[i] = packs[i];
        }
        if (tid < 128) {
            int rr = nodeBase + tid;
            batch_s[tid] = (rr < N) ? batch[rr] : 0;
        }
    }
    __syncthreads();

    const int wv   = tid >> 6;        // 0..7
    const int lane = tid & 63;
    const int wr   = (wv >> 1) * 32;  // 32 rows per wave
    const int half = wv & 1;
    const int wc   = half * 64;
    const int fr   = lane & 15;
    const int fq   = lane >> 4;

    bf16x8 a[4][2];
    #pragma unroll
    for (int kk = 0; kk < 4; ++kk)
        #pragma unroll
        for (int mf = 0; mf < 2; ++mf)
            a[kk][mf] = *(const bf16x8*)&Xs[wr + mf * 16 + fr][kk * 32 + fq * 8];

    float4 w5v  = *(const float4*)(w5p  + half * 64 + fr * 4);
    float4 b45v = *(const float4*)(b45p + half * 64 + fr * 4);

    // ---- pass 1: x3 ----
    {
        f32x4 acc[2][4] = {};
        #pragma unroll
        for (int kk = 0; kk < 4; ++kk) {
            bf16x8 b[4];
            #pragma unroll
            for (int nf = 0; nf < 4; ++nf)
                b[nf] = *(const bf16x8*)(Wbt3 + (size_t)(wc + nf * 16 + fr) * D
                                              + kk * 32 + fq * 8);
            #pragma unroll
            for (int mf = 0; mf < 2; ++mf)
                #pragma unroll
                for (int nf = 0; nf < 4; ++nf)
                    acc[mf][nf] = __builtin_amdgcn_mfma_f32_16x16x32_bf16(
                        a[kk][mf], b[nf], acc[mf][nf], 0, 0, 0);
        }
        float bv[4];
        #pragma unroll
        for (int nf = 0; nf < 4; ++nf) bv[nf] = b3[wc + nf * 16 + fr];

        #pragma unroll
        for (int mf = 0; mf < 2; ++mf) {
            #pragma unroll
            for (int j = 0; j < 4; ++j) {
                int rl  = wr + mf * 16 + fq * 4 + j;
                int row = nodeBase + rl;
                float c0 = acc[mf][0][j] + bv[0];
                float c1 = acc[mf][1][j] + bv[1];
                float c2 = acc[mf][2][j] + bv[2];
                float c3 = acc[mf][3][j] + bv[3];
                uint2 v;
                v.x = pack_bf16(c0, c1);
                v.y = pack_bf16(c2, c3);
                *(uint2*)&X3s[rl][half * 64 + fr * 4] = v;   // permuted cols
                float vp = c0 * w5v.x + c1 * w5v.y + c2 * w5v.z + c3 * w5v.w;
                float vq = c0 * b45v.x + c1 * b45v.y + c2 * b45v.z + c3 * b45v.w;
                #pragma unroll
                for (int off = 1; off < 16; off <<= 1) {
                    vp += __shfl_xor(vp, off);
                    vq += __shfl_xor(vq, off);
                }
                if (fr == 0 && row < N) {
                    atomicAdd(&pq[2 * row],     vp);
                    atomicAdd(&pq[2 * row + 1], vq);
                }
            }
        }
    }
    __syncthreads();

    // ---- pass 2: u = x3 @ W4^T ----
    bf16x8 a2[4][2];
    #pragma unroll
    for (int kk = 0; kk < 4; ++kk)
        #pragma unroll
        for (int mf = 0; mf < 2; ++mf)
            a2[kk][mf] = *(const bf16x8*)&X3s[wr + mf * 16 + fr][kk * 32 + fq * 8];
    __syncthreads();          // all a2 reads done before repack overwrites X3s
    {
        f32x4 acc[2][4] = {};
        #pragma unroll
        for (int kk = 0; kk < 4; ++kk) {
            bf16x8 b[4];
            #pragma unroll
            for (int nf = 0; nf < 4; ++nf)
                b[nf] = *(const bf16x8*)(W4n + (size_t)(wc + nf * 16 + fr) * D
                                             + kk * 32 + fq * 8);
            #pragma unroll
            for (int mf = 0; mf < 2; ++mf)
                #pragma unroll
                for (int nf = 0; nf < 4; ++nf)
                    acc[mf][nf] = __builtin_amdgcn_mfma_f32_16x16x32_bf16(
                        a2[kk][mf], b[nf], acc[mf][nf], 0, 0, 0);
        }
        // repack u into X3s at ORIGINAL k order: k = half*64 + nf*16 + fr
        #pragma unroll
        for (int mf = 0; mf < 2; ++mf)
            #pragma unroll
            for (int nf = 0; nf < 4; ++nf)
                #pragma unroll
                for (int j = 0; j < 4; ++j)
                    X3s[wr + mf * 16 + fq * 4 + j][half * 64 + nf * 16 + fr] =
                        __float2bfloat16(acc[mf][nf][j]);
    }
    __syncthreads();

    // ---- readout u (coalesced) ----
    {
        int r   = tid >> 2;
        int qq  = tid & 3;
        int row = nodeBase + r;
        if (row < N) {
            uint4* dst = (uint4*)(ub + (size_t)row * 64 + qq * 16);
            const uint4* s = (const uint4*)&X3s[r][qq * 32];
            #pragma unroll
            for (int i = 0; i < 4; ++i) dst[i] = s[i];
        }
    }

    // ---- per-graph column sums of X + node counts (run trick) ----
    if (tid < 128) {
        int nv = N - nodeBase; if (nv > 128) nv = 128;
        float s = 0.f, cct = 0.f; int gcur = -1;
        for (int r = 0; r < nv; ++r) {
            int gg = batch_s[r];
            float v = bfbits(*(const unsigned short*)&Xs[r][tid]);
            if (gg != gcur) {
                if (gcur >= 0) {
                    atomicAdd(&xsum[gcur * D + tid], s);
                    if (tid == 0) atomicAdd(&cntn[gcur], cct);
                }
                gcur = gg; s = 0.f; cct = 0.f;
            }
            s += v; cct += 1.f;
        }
        if (gcur >= 0) {
            atomicAdd(&xsum[gcur * D + tid], s);
            if (tid == 0) atomicAdd(&cntn[gcur], cct);
        }
    }
}

// ---------------------------------------------------------------------------
// Stage C: scans
// ---------------------------------------------------------------------------
__global__ __launch_bounds__(256) void scan1(const int* __restrict__ cnt,
                                             int* __restrict__ row_off,
                                             int* __restrict__ bsum, int N)
{
    __shared__ int s[256];
    int tid = threadIdx.x;
    int i0  = blockIdx.x * 1024 + tid * 4;
    int v[4];
    #pragma unroll
    for (int j = 0; j < 4; ++j) v[j] = (i0 + j < N) ? cnt[i0 + j] : 0;
    int t = v[0] + v[1] + v[2] + v[3];
    s[tid] = t;
    __syncthreads();
    for (int off = 1; off < 256; off <<= 1) {
        int y = 0;
        if (tid >= off) y = s[tid - off];
        __syncthreads();
        s[tid] += y;
        __syncthreads();
    }
    int run = s[tid] - t;
    #pragma unroll
    for (int j = 0; j < 4; ++j) {
        if (i0 + j < N) row_off[i0 + j] = run;
        run += v[j];
    }
    if (tid == 255) bsum[blockIdx.x] = s[255];
}

__global__ void scan2(int* __restrict__ bsum, int nb)
{
    int lane = threadIdx.x;  // blockDim = 64
    int a = (lane < nb) ? bsum[lane] : 0;
    int b = (64 + lane < nb) ? bsum[64 + lane] : 0;
    int xa = a;
    #pragma unroll
    for (int off = 1; off < 64; off <<= 1) {
        int y = __shfl_up(xa, off);
        if (lane >= off) xa += y;
    }
    int totA = __shfl(xa, 63);
    int xb2 = b;
    #pragma unroll
    for (int off = 1; off < 64; off <<= 1) {
        int y = __shfl_up(xb2, off);
        if (lane >= off) xb2 += y;
    }
    if (lane < nb) bsum[lane] = xa - a;
    if (64 + lane < nb) bsum[64 + lane] = totA + xb2 - b;
}

// ---------------------------------------------------------------------------
// Stage D: fill (row_off doubles as cursor; node recovers start later)
// ---------------------------------------------------------------------------
__global__ void fill_kernel(const int* __restrict__ srcIdx,
                            const int* __restrict__ dstIdx,
                            const float* __restrict__ eattr,
                            int* __restrict__ row_off,
                            const int* __restrict__ bsum,
                            int2* __restrict__ src_attr, int E)
{
    int e = blockIdx.x * 256 + threadIdx.x;
    if (e < E) {
        int d = dstIdx[e];
        int p = atomicAdd(&row_off[d], 1);
        int2 rec;
        rec.x = srcIdx[e];
        rec.y = __float_as_int(eattr[e]);
        src_attr[p + bsum[d >> 10]] = rec;
    }
}

// ---------------------------------------------------------------------------
// Stage E: per-dst-node attention + aggregation + in-kernel mean-pool of
// z = sum alpha * X[src]. One wave per node (chunked), single uint2 gather
// per edge per lane (xb serves dot AND value). Per-block LDS pool, one flush.
// ---------------------------------------------------------------------------
__global__ __launch_bounds__(256) void node_kernel(
    const unsigned* __restrict__ xb,           // [N][64]
    const unsigned* __restrict__ ub,           // [N][64]
    const float* __restrict__ pq,              // [N][2]
    const int* __restrict__ row_off,
    const int* __restrict__ cnt,
    const int* __restrict__ bsum,
    const int2* __restrict__ src_attr,
    const int* __restrict__ batch,
    float* __restrict__ poolZ,                 // [16][128], pre-zeroed
    float* __restrict__ cnt2g,                 // [16], pre-zeroed
    int N, int chunk)
{
    __shared__ float zs[NGRAPH * D];
    __shared__ float c2s[NGRAPH];
    for (int i = threadIdx.x; i < NGRAPH * D; i += 256) zs[i] = 0.f;
    if (threadIdx.x < NGRAPH) c2s[threadIdx.x] = 0.f;
    __syncthreads();

    const int wv   = threadIdx.x >> 6;
    const int lane = threadIdx.x & 63;
    const int h    = lane >> 5;
    const int l5   = lane & 31;
    const float inv_sqrt_d = 0.08838834764831845f;  // 1/sqrt(128)

    int startN = blockIdx.x * chunk;
    int endN   = min(startN + chunk, N);

    for (int n = startN + wv; n < endN; n += 4) {
        int deg = cnt[n];
        if (deg <= 0) continue;                // wave-uniform

        uint2 uu = *(const uint2*)(ub + (size_t)n * 64 + l5 * 2);
        float u0 = bflo(uu.x), u1 = bfhi(uu.x), u2 = bflo(uu.y), u3 = bfhi(uu.y);
        float pv = pq[2 * n], qv = pq[2 * n + 1];
        const int2* sa = src_attr + (row_off[n] + bsum[n >> 10] - deg);

        float mrun = -INFINITY, z = 0.f;
        float acc0 = 0.f, acc1 = 0.f, acc2 = 0.f, acc3 = 0.f;

        for (int i = 0; i < deg; i += 4) {
            int e0 = i + h;
            int e1 = i + 2 + h;
            int2 r0 = sa[min(e0, deg - 1)];
            int2 r1 = sa[min(e1, deg - 1)];
            uint2 f0 = *(const uint2*)(xb + (size_t)r0.x * 64 + l5 * 2);
            uint2 f1 = *(const uint2*)(xb + (size_t)r1.x * 64 + l5 * 2);

            float d0 = u0 * bflo(f0.x) + u1 * bfhi(f0.x) + u2 * bflo(f0.y) + u3 * bfhi(f0.y);
            float d1 = u0 * bflo(f1.x) + u1 * bfhi(f1.x) + u2 * bflo(f1.y) + u3 * bfhi(f1.y);
            #pragma unroll
            for (int off = 16; off; off >>= 1) {
                d0 += __shfl_xor(d0, off);
                d1 += __shfl_xor(d1, off);
            }
            float s0 = (d0 + __int_as_float(r0.y) * pv + qv) * inv_sqrt_d;
            float s1 = (d1 + __int_as_float(r1.y) * pv + qv) * inv_sqrt_d;
            if (e0 >= deg) s0 = -INFINITY;
            if (e1 >= deg) s1 = -INFINITY;

            float tm = fmaxf(s0, s1);
            tm = fmaxf(tm, __shfl_xor(tm, 32));
            if (tm > mrun) {                   // wave-uniform rescale branch
                float sc = __expf(mrun - tm);  // 0 on first iteration
                z *= sc; acc0 *= sc; acc1 *= sc; acc2 *= sc; acc3 *= sc;
                mrun = tm;
            }
            float w0 = __expf(s0 - mrun);      // 0 for masked edges
            float w1 = __expf(s1 - mrun);
            z += w0 + w1;
            acc0 += w0 * bflo(f0.x) + w1 * bflo(f1.x);
            acc1 += w0 * bfhi(f0.x) + w1 * bfhi(f1.x);
            acc2 += w0 * bflo(f0.y) + w1 * bflo(f1.y);
            acc3 += w0 * bfhi(f0.y) + w1 * bfhi(f1.y);
        }

        z    += __shfl_xor(z, 32);
        acc0 += __shfl_xor(acc0, 32);
        acc1 += __shfl_xor(acc1, 32);
        acc2 += __shfl_xor(acc2, 32);
        acc3 += __shfl_xor(acc3, 32);

        if (h == 0) {
            float inv = 1.f / z;
            int g = batch[n];
            float* zr = zs + g * D + l5 * 4;
            atomicAdd(zr + 0, acc0 * inv);
            atomicAdd(zr + 1, acc1 * inv);
            atomicAdd(zr + 2, acc2 * inv);
            atomicAdd(zr + 3, acc3 * inv);
            if (l5 == 0) atomicAdd(&c2s[g], 1.f);
        }
    }
    __syncthreads();
    for (int i = threadIdx.x; i < NGRAPH * D; i += 256) {
        float v = zs[i];
        if (v != 0.f) atomicAdd(&poolZ[i], v);
    }
    if (threadIdx.x < NGRAPH) {
        float v = c2s[threadIdx.x];
        if (v != 0.f) atomicAdd(&cnt2g[threadIdx.x], v);
    }
}

// ---------------------------------------------------------------------------
// final: out[g][c] = (xsum.W1col + cntn*b1 + Zsum.W2col + cnt2*b2) / max(cntn,1)
// ---------------------------------------------------------------------------
__global__ void final_kernel(const float* __restrict__ xsum,
                             const float* __restrict__ poolZ,
                             const float* __restrict__ cntn,
                             const float* __restrict__ cnt2g,
                             const float* __restrict__ W1,
                             const float* __restrict__ b1,
                             const float* __restrict__ W2,
                             const float* __restrict__ b2,
                             float* __restrict__ out)
{
    int i = blockIdx.x * 256 + threadIdx.x;
    if (i < NGRAPH * D) {
        int g = i >> 7;
        int c = i & 127;
        float s1 = 0.f, s2 = 0.f;
        for (int k = 0; k < D; ++k) {
            s1 += xsum[g * D + k]  * W1[k * D + c];
            s2 += poolZ[g * D + k] * W2[k * D + c];
        }
        float cval = cntn[g];
        out[i] = (s1 + cval * b1[c] + s2 + cnt2g[g] * b2[c]) / fmaxf(cval, 1.f);
    }
}

// ---------------------------------------------------------------------------
extern "C" void kernel_launch(void* const* d_in, const int* in_sizes, int n_in,
                              void* d_out, int out_size, void* d_ws, size_t ws_size,
                              hipStream_t stream)
{
    const float* x     = (const float*)d_in[0];
    const int*   eidx  = (const int*)d_in[1];   // [2,E]: src = eidx[e], dst = eidx[E+e]
    const float* eattr = (const float*)d_in[2];
    const int*   batch = (const int*)d_in[3];
    const float* W1 = (const float*)d_in[4];  const float* b1 = (const float*)d_in[5];
    const float* W2 = (const float*)d_in[6];  const float* b2 = (const float*)d_in[7];
    const float* W3 = (const float*)d_in[8];  const float* b3 = (const float*)d_in[9];
    const float* W4 = (const float*)d_in[10]; const float* b4 = (const float*)d_in[11];
    const float* W5 = (const float*)d_in[12]; const float* b5 = (const float*)d_in[13];
    float* out = (float*)d_out;

    const int N = in_sizes[0] / D;
    const int E = in_sizes[1] / 2;

    // workspace layout
    char* ws = (char*)d_ws;
    unsigned* xb = (unsigned*)ws;                           // [N][64]
    unsigned* ub = xb + (size_t)N * 64;                     // [N][64]
    int* cnt      = (int*)(ub + (size_t)N * 64);
    int* row_off  = cnt + N;
    int2* src_attr = (int2*)(row_off + N);
    int* bsum     = (int*)(src_attr + E);
    // zero region: poolZ | xsum | cntn | cnt2 | pq
    float* poolZ = (float*)(bsum + 256);
    float* xsum  = poolZ + NGRAPH * D;
    float* cntn  = xsum + NGRAPH * D;
    float* cnt2g = cntn + NGRAPH;
    float* pq    = cnt2g + NGRAPH;                          // [N][2]
    __hip_bfloat16* Wbt3 = (__hip_bfloat16*)(pq + 2 * (size_t)N);
    __hip_bfloat16* W4n  = Wbt3 + D * D;
    float* w5p  = (float*)(W4n + D * D);
    float* b45p = w5p + D;

    size_t zero_floats = (size_t)(2 * NGRAPH * D + 2 * NGRAPH) + 2 * (size_t)N;
    hipMemsetAsync(cnt, 0, (size_t)N * sizeof(int), stream);
    hipMemsetAsync(poolZ, 0, zero_floats * sizeof(float), stream);

    count_wconv_kernel<<<(E + 255) / 256, 256, 0, stream>>>(
        eidx + E, cnt, E, W3, W4, W5, b4, b5, Wbt3, W4n, w5p, b45p);

    int nb = (N + 1023) / 1024;
    scan1<<<nb, 256, 0, stream>>>(cnt, row_off, bsum, N);
    scan2<<<1, 64, 0, stream>>>(bsum, nb);
    fill_kernel<<<(E + 255) / 256, 256, 0, stream>>>(eidx, eidx + E, eattr,
                                                     row_off, bsum, src_attr, E);

    proj10_kernel<<<(N + 127) / 128, 512, 0, stream>>>(x, Wbt3, W4n, b3,
                                                       w5p, b45p, batch,
                                                       xb, ub, pq, xsum, cntn, N);

    const int nodeBlocks = 2048;
    int chunk = (N + nodeBlocks - 1) / nodeBlocks;
    node_kernel<<<nodeBlocks, 256, 0, stream>>>(xb, ub, pq, row_off, cnt, bsum,
                                                src_attr, batch, poolZ, cnt2g,
                                                N, chunk);

    final_kernel<<<(NGRAPH * D + 255) / 256, 256, 0, stream>>>(
        xsum, poolZ, cntn, cnt2g, W1, b1, W2, b2, out);
}

// Round 12
// 250.786 us; speedup vs baseline: 6.0585x; 1.0564x over previous
//
#include <hip/hip_runtime.h>
#include <hip/hip_bf16.h>
#include <math.h>

#define D 128
#define NGRAPH 16

typedef __attribute__((ext_vector_type(8))) short bf16x8;   // 8 bf16 (4 VGPRs)
typedef __attribute__((ext_vector_type(4))) float f32x4;    // MFMA C/D

// Contraction-dim permutation (internal only): permuted index c' holds
// original col pi(c') = (c'>>6)*64 + (c'&3)*16 + ((c'>>2)&15).
// x3 lives only in LDS (permuted cols); W4n's contraction dim is permuted to
// match; u, xb, zb are in ORIGINAL column order -> no unpermute anywhere.

__device__ __forceinline__ float bflo(unsigned u) {
    union { unsigned i; float f; } v; v.i = u << 16; return v.f;
}
__device__ __forceinline__ float bfhi(unsigned u) {
    union { unsigned i; float f; } v; v.i = u & 0xffff0000u; return v.f;
}
__device__ __forceinline__ float bfbits(unsigned short us) {
    union { unsigned i; float f; } v; v.i = ((unsigned)us) << 16; return v.f;
}
__device__ __forceinline__ unsigned pack_bf16(float x, float y) {
    __hip_bfloat16 hx = __float2bfloat16(x);
    __hip_bfloat16 hy = __float2bfloat16(y);
    unsigned ux = *(const unsigned short*)&hx;
    unsigned uy = *(const unsigned short*)&hy;
    return ux | (uy << 16);
}
__device__ __forceinline__ int unperm(int cp) {
    return (cp >> 6) * 64 + (cp & 3) * 16 + ((cp >> 2) & 15);
}

// ---------------------------------------------------------------------------
// Stage A: edge count by dst + weight prep
// ---------------------------------------------------------------------------
__global__ void count_wconv_kernel(const int* __restrict__ dstIdx,
                                   int* __restrict__ cnt, int E,
                                   const float* __restrict__ W3,
                                   const float* __restrict__ W4,
                                   const float* __restrict__ W5,
                                   const float* __restrict__ b4,
                                   const float* __restrict__ b5,
                                   __hip_bfloat16* __restrict__ Wbt3,
                                   __hip_bfloat16* __restrict__ W4n,
                                   float* __restrict__ w5p,
                                   float* __restrict__ b45p)
{
    int id = blockIdx.x * 256 + threadIdx.x;
    if (id < E) atomicAdd(&cnt[dstIdx[id]], 1);
    if (id < D * D) {
        int c = id >> 7, k = id & 127;
        Wbt3[id] = __float2bfloat16(W3[k * D + c]);
        W4n[id]  = __float2bfloat16(W4[c * D + unperm(k)]);  // row c=k-out, col k=c'
    }
    if (id < D) {
        int c = unperm(id);
        w5p[id]  = W5[c];
        b45p[id] = b4[c] + b5[c];
    }
}

// ---------------------------------------------------------------------------
// Stage B: chained GEMMs. Pass1: x3 = Xs@W3 + b3 (LDS, permuted cols; p,q
// reduced + atomicAdd'ed to pq). Pass2: u = x3@W4^T, repacked to original k.
// xb = bf16(X) written from staging registers. Tail (run trick): xsum
// per-graph column sums + cntn (node counts) + cnt2g (deg>0 counts).
// ---------------------------------------------------------------------------
__global__ __launch_bounds__(512, 4) void proj10_kernel(
    const float* __restrict__ X,
    const __hip_bfloat16* __restrict__ Wbt3,
    const __hip_bfloat16* __restrict__ W4n,
    const float* __restrict__ b3,
    const float* __restrict__ w5p, const float* __restrict__ b45p,
    const int* __restrict__ batch,
    const int* __restrict__ cnt,
    unsigned* __restrict__ xb,       // [N][64] uints, original cols
    unsigned* __restrict__ ub,       // [N][64] uints, original k
    float* __restrict__ pq,          // [N][2], pre-zeroed
    float* __restrict__ xsum,        // [16][128] fp32, pre-zeroed
    float* __restrict__ cntn,        // [16] fp32, pre-zeroed
    float* __restrict__ cnt2g,       // [16] fp32, pre-zeroed
    int N)
{
    __shared__ __hip_bfloat16 Xs[128][136];
    __shared__ __hip_bfloat16 X3s[128][136];
    __shared__ int batch_s[128];
    __shared__ int deg_s[128];

    const int nodeBase = blockIdx.x * 128;
    const int tid      = threadIdx.x;

    // ---- stage X -> Xs (bf16) and write xb directly (coalesced) ----
    {
        int r   = tid >> 2;
        int qq  = tid & 3;
        int row = nodeBase + r;
        int rowc = (row < N) ? row : N - 1;
        const float* src = X + (size_t)rowc * D + qq * 32;
        uint4 packs[4];
        #pragma unroll
        for (int i = 0; i < 4; ++i) {
            float4 u = *(const float4*)(src + i * 8);
            float4 v = *(const float4*)(src + i * 8 + 4);
            packs[i].x = pack_bf16(u.x, u.y);
            packs[i].y = pack_bf16(u.z, u.w);
            packs[i].z = pack_bf16(v.x, v.y);
            packs[i].w = pack_bf16(v.z, v.w);
            *(uint4*)&Xs[r][qq * 32 + i * 8] = packs[i];
        }
        if (row < N) {
            uint4* dst = (uint4*)(xb + (size_t)row * 64 + qq * 16);
            #pragma unroll
            for (int i = 0; i < 4; ++i) dst[i] = packs[i];
        }
        if (tid < 128) {
            int rr = nodeBase + tid;
            batch_s[tid] = (rr < N) ? batch[rr] : 0;
        } else if (tid < 256) {
            int rr = nodeBase + tid - 128;
            deg_s[tid - 128] = (rr < N) ? cnt[rr] : 0;
        }
    }
    __syncthreads();

    const int wv   = tid >> 6;        // 0..7
    const int lane = tid & 63;
    const int wr   = (wv >> 1) * 32;  // 32 rows per wave
    const int half = wv & 1;
    const int wc   = half * 64;
    const int fr   = lane & 15;
    const int fq   = lane >> 4;

    bf16x8 a[4][2];
    #pragma unroll
    for (int kk = 0; kk < 4; ++kk)
        #pragma unroll
        for (int mf = 0; mf < 2; ++mf)
            a[kk][mf] = *(const bf16x8*)&Xs[wr + mf * 16 + fr][kk * 32 + fq * 8];

    float4 w5v  = *(const float4*)(w5p  + half * 64 + fr * 4);
    float4 b45v = *(const float4*)(b45p + half * 64 + fr * 4);

    // ---- pass 1: x3 ----
    {
        f32x4 acc[2][4] = {};
        #pragma unroll
        for (int kk = 0; kk < 4; ++kk) {
            bf16x8 b[4];
            #pragma unroll
            for (int nf = 0; nf < 4; ++nf)
                b[nf] = *(const bf16x8*)(Wbt3 + (size_t)(wc + nf * 16 + fr) * D
                                              + kk * 32 + fq * 8);
            #pragma unroll
            for (int mf = 0; mf < 2; ++mf)
                #pragma unroll
                for (int nf = 0; nf < 4; ++nf)
                    acc[mf][nf] = __builtin_amdgcn_mfma_f32_16x16x32_bf16(
                        a[kk][mf], b[nf], acc[mf][nf], 0, 0, 0);
        }
        float bv[4];
        #pragma unroll
        for (int nf = 0; nf < 4; ++nf) bv[nf] = b3[wc + nf * 16 + fr];

        #pragma unroll
        for (int mf = 0; mf < 2; ++mf) {
            #pragma unroll
            for (int j = 0; j < 4; ++j) {
                int rl  = wr + mf * 16 + fq * 4 + j;
                int row = nodeBase + rl;
                float c0 = acc[mf][0][j] + bv[0];
                float c1 = acc[mf][1][j] + bv[1];
                float c2 = acc[mf][2][j] + bv[2];
                float c3 = acc[mf][3][j] + bv[3];
                uint2 v;
                v.x = pack_bf16(c0, c1);
                v.y = pack_bf16(c2, c3);
                *(uint2*)&X3s[rl][half * 64 + fr * 4] = v;   // permuted cols
                float vp = c0 * w5v.x + c1 * w5v.y + c2 * w5v.z + c3 * w5v.w;
                float vq = c0 * b45v.x + c1 * b45v.y + c2 * b45v.z + c3 * b45v.w;
                #pragma unroll
                for (int off = 1; off < 16; off <<= 1) {
                    vp += __shfl_xor(vp, off);
                    vq += __shfl_xor(vq, off);
                }
                if (fr == 0 && row < N) {
                    atomicAdd(&pq[2 * row],     vp);
                    atomicAdd(&pq[2 * row + 1], vq);
                }
            }
        }
    }
    __syncthreads();

    // ---- pass 2: u = x3 @ W4^T ----
    bf16x8 a2[4][2];
    #pragma unroll
    for (int kk = 0; kk < 4; ++kk)
        #pragma unroll
        for (int mf = 0; mf < 2; ++mf)
            a2[kk][mf] = *(const bf16x8*)&X3s[wr + mf * 16 + fr][kk * 32 + fq * 8];
    __syncthreads();          // all a2 reads done before repack overwrites X3s
    {
        f32x4 acc[2][4] = {};
        #pragma unroll
        for (int kk = 0; kk < 4; ++kk) {
            bf16x8 b[4];
            #pragma unroll
            for (int nf = 0; nf < 4; ++nf)
                b[nf] = *(const bf16x8*)(W4n + (size_t)(wc + nf * 16 + fr) * D
                                             + kk * 32 + fq * 8);
            #pragma unroll
            for (int mf = 0; mf < 2; ++mf)
                #pragma unroll
                for (int nf = 0; nf < 4; ++nf)
                    acc[mf][nf] = __builtin_amdgcn_mfma_f32_16x16x32_bf16(
                        a2[kk][mf], b[nf], acc[mf][nf], 0, 0, 0);
        }
        // repack u into X3s at ORIGINAL k order: k = half*64 + nf*16 + fr
        #pragma unroll
        for (int mf = 0; mf < 2; ++mf)
            #pragma unroll
            for (int nf = 0; nf < 4; ++nf)
                #pragma unroll
                for (int j = 0; j < 4; ++j)
                    X3s[wr + mf * 16 + fq * 4 + j][half * 64 + nf * 16 + fr] =
                        __float2bfloat16(acc[mf][nf][j]);
    }
    __syncthreads();

    // ---- readout u (coalesced) ----
    {
        int r   = tid >> 2;
        int qq  = tid & 3;
        int row = nodeBase + r;
        if (row < N) {
            uint4* dst = (uint4*)(ub + (size_t)row * 64 + qq * 16);
            const uint4* s = (const uint4*)&X3s[r][qq * 32];
            #pragma unroll
            for (int i = 0; i < 4; ++i) dst[i] = s[i];
        }
    }

    // ---- per-graph column sums of X + node counts + deg>0 counts ----
    if (tid < 128) {
        int nv = N - nodeBase; if (nv > 128) nv = 128;
        float s = 0.f, cct = 0.f, cc2 = 0.f; int gcur = -1;
        for (int r = 0; r < nv; ++r) {
            int gg = batch_s[r];
            float v = bfbits(*(const unsigned short*)&Xs[r][tid]);
            if (gg != gcur) {
                if (gcur >= 0) {
                    atomicAdd(&xsum[gcur * D + tid], s);
                    if (tid == 0) {
                        atomicAdd(&cntn[gcur], cct);
                        atomicAdd(&cnt2g[gcur], cc2);
                    }
                }
                gcur = gg; s = 0.f; cct = 0.f; cc2 = 0.f;
            }
            s += v; cct += 1.f;
            if (tid == 0 && deg_s[r] > 0) cc2 += 1.f;
        }
        if (gcur >= 0) {
            atomicAdd(&xsum[gcur * D + tid], s);
            if (tid == 0) {
                atomicAdd(&cntn[gcur], cct);
                atomicAdd(&cnt2g[gcur], cc2);
            }
        }
    }
}

// ---------------------------------------------------------------------------
// Stage C: scans
// ---------------------------------------------------------------------------
__global__ __launch_bounds__(256) void scan1(const int* __restrict__ cnt,
                                             int* __restrict__ row_off,
                                             int* __restrict__ bsum, int N)
{
    __shared__ int s[256];
    int tid = threadIdx.x;
    int i0  = blockIdx.x * 1024 + tid * 4;
    int v[4];
    #pragma unroll
    for (int j = 0; j < 4; ++j) v[j] = (i0 + j < N) ? cnt[i0 + j] : 0;
    int t = v[0] + v[1] + v[2] + v[3];
    s[tid] = t;
    __syncthreads();
    for (int off = 1; off < 256; off <<= 1) {
        int y = 0;
        if (tid >= off) y = s[tid - off];
        __syncthreads();
        s[tid] += y;
        __syncthreads();
    }
    int run = s[tid] - t;
    #pragma unroll
    for (int j = 0; j < 4; ++j) {
        if (i0 + j < N) row_off[i0 + j] = run;
        run += v[j];
    }
    if (tid == 255) bsum[blockIdx.x] = s[255];
}

__global__ void scan2(int* __restrict__ bsum, int nb)
{
    int lane = threadIdx.x;  // blockDim = 64
    int a = (lane < nb) ? bsum[lane] : 0;
    int b = (64 + lane < nb) ? bsum[64 + lane] : 0;
    int xa = a;
    #pragma unroll
    for (int off = 1; off < 64; off <<= 1) {
        int y = __shfl_up(xa, off);
        if (lane >= off) xa += y;
    }
    int totA = __shfl(xa, 63);
    int xb2 = b;
    #pragma unroll
    for (int off = 1; off < 64; off <<= 1) {
        int y = __shfl_up(xb2, off);
        if (lane >= off) xb2 += y;
    }
    if (lane < nb) bsum[lane] = xa - a;
    if (64 + lane < nb) bsum[64 + lane] = totA + xb2 - b;
}

// ---------------------------------------------------------------------------
// Stage D: fill (row_off doubles as cursor; node recovers start later)
// ---------------------------------------------------------------------------
__global__ void fill_kernel(const int* __restrict__ srcIdx,
                            const int* __restrict__ dstIdx,
                            const float* __restrict__ eattr,
                            int* __restrict__ row_off,
                            const int* __restrict__ bsum,
                            int2* __restrict__ src_attr, int E)
{
    int e = blockIdx.x * 256 + threadIdx.x;
    if (e < E) {
        int d = dstIdx[e];
        int p = atomicAdd(&row_off[d], 1);
        int2 rec;
        rec.x = srcIdx[e];
        rec.y = __float_as_int(eattr[e]);
        src_attr[p + bsum[d >> 10]] = rec;
    }
}

// ---------------------------------------------------------------------------
// Stage E: per-dst-node attention + aggregation. ONE WAVE PER NODE (round-9
// structure: short-lived waves, zero LDS, plain coalesced store). Single
// uint2 gather per edge per lane (xb serves dot AND value). Writes
// z_n = sum alpha * X[src] as bf16 (zeros for deg=0).
// ---------------------------------------------------------------------------
__global__ __launch_bounds__(256) void node_kernel(
    unsigned* __restrict__ zb,                 // [N][64]; write-only
    const unsigned* __restrict__ xb,           // [N][64]
    const unsigned* __restrict__ ub,           // [N][64]
    const float* __restrict__ pq,              // [N][2]
    const int* __restrict__ row_off,
    const int* __restrict__ cnt,
    const int* __restrict__ bsum,
    const int2* __restrict__ src_attr,
    int N)
{
    int n    = blockIdx.x * 4 + (threadIdx.x >> 6);
    int lane = threadIdx.x & 63;
    if (n >= N) return;
    int h  = lane >> 5;
    int l5 = lane & 31;

    uint2 uu = *(const uint2*)(ub + (size_t)n * 64 + l5 * 2);
    float u0 = bflo(uu.x), u1 = bfhi(uu.x), u2 = bflo(uu.y), u3 = bfhi(uu.y);
    float pv = pq[2 * n], qv = pq[2 * n + 1];

    const int deg   = cnt[n];
    const int start = row_off[n] + bsum[n >> 10] - deg;
    const int2* sa  = src_attr + start;
    const float inv_sqrt_d = 0.08838834764831845f;  // 1/sqrt(128)

    float mrun = -INFINITY, z = 0.f;
    float acc0 = 0.f, acc1 = 0.f, acc2 = 0.f, acc3 = 0.f;

    for (int i = 0; i < deg; i += 4) {
        int e0 = i + h;
        int e1 = i + 2 + h;
        int2 r0 = sa[min(e0, deg - 1)];
        int2 r1 = sa[min(e1, deg - 1)];
        uint2 f0 = *(const uint2*)(xb + (size_t)r0.x * 64 + l5 * 2);
        uint2 f1 = *(const uint2*)(xb + (size_t)r1.x * 64 + l5 * 2);

        float d0 = u0 * bflo(f0.x) + u1 * bfhi(f0.x) + u2 * bflo(f0.y) + u3 * bfhi(f0.y);
        float d1 = u0 * bflo(f1.x) + u1 * bfhi(f1.x) + u2 * bflo(f1.y) + u3 * bfhi(f1.y);
        #pragma unroll
        for (int off = 16; off; off >>= 1) {
            d0 += __shfl_xor(d0, off);
            d1 += __shfl_xor(d1, off);
        }
        float s0 = (d0 + __int_as_float(r0.y) * pv + qv) * inv_sqrt_d;
        float s1 = (d1 + __int_as_float(r1.y) * pv + qv) * inv_sqrt_d;
        if (e0 >= deg) s0 = -INFINITY;
        if (e1 >= deg) s1 = -INFINITY;

        float tm = fmaxf(s0, s1);
        tm = fmaxf(tm, __shfl_xor(tm, 32));
        if (tm > mrun) {                       // wave-uniform rescale branch
            float sc = __expf(mrun - tm);      // 0 on first iteration
            z *= sc; acc0 *= sc; acc1 *= sc; acc2 *= sc; acc3 *= sc;
            mrun = tm;
        }
        float w0 = __expf(s0 - mrun);          // 0 for masked edges
        float w1 = __expf(s1 - mrun);
        z += w0 + w1;
        acc0 += w0 * bflo(f0.x) + w1 * bflo(f1.x);
        acc1 += w0 * bfhi(f0.x) + w1 * bfhi(f1.x);
        acc2 += w0 * bflo(f0.y) + w1 * bflo(f1.y);
        acc3 += w0 * bfhi(f0.y) + w1 * bfhi(f1.y);
    }

    z    += __shfl_xor(z, 32);
    acc0 += __shfl_xor(acc0, 32);
    acc1 += __shfl_xor(acc1, 32);
    acc2 += __shfl_xor(acc2, 32);
    acc3 += __shfl_xor(acc3, 32);

    if (h == 0) {
        float o0 = 0.f, o1 = 0.f, o2 = 0.f, o3 = 0.f;
        if (deg > 0) {
            float inv = 1.f / z;
            o0 = acc0 * inv; o1 = acc1 * inv; o2 = acc2 * inv; o3 = acc3 * inv;
        }
        uint2 o; o.x = pack_bf16(o0, o1); o.y = pack_bf16(o2, o3);
        *(uint2*)(zb + (size_t)n * 64 + l5 * 2) = o;
    }
}

// ---------------------------------------------------------------------------
// Stage F: global mean pool of zb (original column order, batch sorted ->
// register accumulate, flush on graph change).
// ---------------------------------------------------------------------------
__global__ __launch_bounds__(256) void pool_kernel(
    const unsigned* __restrict__ zb,           // [N][64] uints
    const int* __restrict__ batch,
    float* __restrict__ poolZ,
    int N)
{
    int c   = threadIdx.x & 63;
    int sub = threadIdx.x >> 6;
    int nodesPerBlock = (N + gridDim.x - 1) / gridDim.x;
    int startN = blockIdx.x * nodesPerBlock;
    int endN   = min(startN + nodesPerBlock, N);

    float ax = 0.f, ay = 0.f;
    int gcur = -1;
    for (int n = startN + sub; n < endN; n += 4) {
        int gg = batch[n];
        unsigned u = zb[(size_t)n * 64 + c];
        if (gg != gcur) {
            if (gcur >= 0) {
                atomicAdd(&poolZ[gcur * D + c * 2], ax);
                atomicAdd(&poolZ[gcur * D + c * 2 + 1], ay);
            }
            gcur = gg; ax = 0.f; ay = 0.f;
        }
        ax += bflo(u); ay += bfhi(u);
    }
    if (gcur >= 0) {
        atomicAdd(&poolZ[gcur * D + c * 2], ax);
        atomicAdd(&poolZ[gcur * D + c * 2 + 1], ay);
    }
}

// ---------------------------------------------------------------------------
// final: out[g][c] = (xsum.W1col + cntn*b1 + Zsum.W2col + cnt2*b2) / max(cntn,1)
// ---------------------------------------------------------------------------
__global__ void final_kernel(const float* __restrict__ xsum,
                             const float* __restrict__ poolZ,
                             const float* __restrict__ cntn,
                             const float* __restrict__ cnt2g,
                             const float* __restrict__ W1,
                             const float* __restrict__ b1,
                             const float* __restrict__ W2,
                             const float* __restrict__ b2,
                             float* __restrict__ out)
{
    int i = blockIdx.x * 256 + threadIdx.x;
    if (i < NGRAPH * D) {
        int g = i >> 7;
        int c = i & 127;
        float s1 = 0.f, s2 = 0.f;
        for (int k = 0; k < D; ++k) {
            s1 += xsum[g * D + k]  * W1[k * D + c];
            s2 += poolZ[g * D + k] * W2[k * D + c];
        }
        float cval = cntn[g];
        out[i] = (s1 + cval * b1[c] + s2 + cnt2g[g] * b2[c]) / fmaxf(cval, 1.f);
    }
}

// ---------------------------------------------------------------------------
extern "C" void kernel_launch(void* const* d_in, const int* in_sizes, int n_in,
                              void* d_out, int out_size, void* d_ws, size_t ws_size,
                              hipStream_t stream)
{
    const float* x     = (const float*)d_in[0];
    const int*   eidx  = (const int*)d_in[1];   // [2,E]: src = eidx[e], dst = eidx[E+e]
    const float* eattr = (const float*)d_in[2];
    const int*   batch = (const int*)d_in[3];
    const float* W1 = (const float*)d_in[4];  const float* b1 = (const float*)d_in[5];
    const float* W2 = (const float*)d_in[6];  const float* b2 = (const float*)d_in[7];
    const float* W3 = (const float*)d_in[8];  const float* b3 = (const float*)d_in[9];
    const float* W4 = (const float*)d_in[10]; const float* b4 = (const float*)d_in[11];
    const float* W5 = (const float*)d_in[12]; const float* b5 = (const float*)d_in[13];
    float* out = (float*)d_out;

    const int N = in_sizes[0] / D;
    const int E = in_sizes[1] / 2;

    // workspace layout
    char* ws = (char*)d_ws;
    unsigned* xb = (unsigned*)ws;                           // [N][64]
    unsigned* ub = xb + (size_t)N * 64;                     // [N][64]
    unsigned* zb = ub + (size_t)N * 64;                     // [N][64]
    int* cnt      = (int*)(zb + (size_t)N * 64);
    int* row_off  = cnt + N;
    int2* src_attr = (int2*)(row_off + N);
    int* bsum     = (int*)(src_attr + E);
    // zero region: poolZ | xsum | cntn | cnt2 | pq
    float* poolZ = (float*)(bsum + 256);
    float* xsum  = poolZ + NGRAPH * D;
    float* cntn  = xsum + NGRAPH * D;
    float* cnt2g = cntn + NGRAPH;
    float* pq    = cnt2g + NGRAPH;                          // [N][2]
    __hip_bfloat16* Wbt3 = (__hip_bfloat16*)(pq + 2 * (size_t)N);
    __hip_bfloat16* W4n  = Wbt3 + D * D;
    float* w5p  = (float*)(W4n + D * D);
    float* b45p = w5p + D;

    size_t zero_floats = (size_t)(2 * NGRAPH * D + 2 * NGRAPH) + 2 * (size_t)N;
    hipMemsetAsync(cnt, 0, (size_t)N * sizeof(int), stream);
    hipMemsetAsync(poolZ, 0, zero_floats * sizeof(float), stream);

    count_wconv_kernel<<<(E + 255) / 256, 256, 0, stream>>>(
        eidx + E, cnt, E, W3, W4, W5, b4, b5, Wbt3, W4n, w5p, b45p);

    int nb = (N + 1023) / 1024;
    scan1<<<nb, 256, 0, stream>>>(cnt, row_off, bsum, N);
    scan2<<<1, 64, 0, stream>>>(bsum, nb);
    fill_kernel<<<(E + 255) / 256, 256, 0, stream>>>(eidx, eidx + E, eattr,
                                                     row_off, bsum, src_attr, E);

    proj10_kernel<<<(N + 127) / 128, 512, 0, stream>>>(x, Wbt3, W4n, b3,
                                                       w5p, b45p, batch, cnt,
                                                       xb, ub, pq, xsum,
                                                       cntn, cnt2g, N);

    node_kernel<<<(N + 3) / 4, 256, 0, stream>>>(zb, xb, ub, pq, row_off, cnt,
                                                 bsum, src_attr, N);

    pool_kernel<<<256, 256, 0, stream>>>(zb, batch, poolZ, N);

    final_kernel<<<(NGRAPH * D + 255) / 256, 256, 0, stream>>>(
        xsum, poolZ, cntn, cnt2g, W1, b1, W2, b2, out);
}